// Round 2
// baseline (8083.317 us; speedup 1.0000x reference)
//
#include <hip/hip_runtime.h>

#define NN 50000
#define EE 800000
#define DD 128
#define RR 8
#define TILE_E 64
#define MAX_TILES (EE / TILE_E + RR)   // upper bound on sum_r ceil(E_r/64)

// ---------------- small prep kernels ----------------

__global__ void count_and_hist(const int* __restrict__ dst, const int* __restrict__ et,
                               float* __restrict__ cnt, int* __restrict__ rcnt) {
    int e = blockIdx.x * blockDim.x + threadIdx.x;
    int lane = threadIdx.x & 63;
    int r = (e < EE) ? et[e] : -1;
    if (e < EE) atomicAdd(&cnt[dst[e] * RR + r], 1.0f);
    // wave-aggregated relation histogram: 8 ballots, <=8 atomics per wave
    for (int rr = 0; rr < RR; ++rr) {
        unsigned long long mask = __ballot(r == rr);
        if (mask == 0ull) continue;
        int leader = __ffsll((unsigned long long)mask) - 1;
        if (lane == leader) atomicAdd(&rcnt[rr], __popcll(mask));
    }
}

__global__ void invert_cnt(float* __restrict__ cnt) {
    int i = blockIdx.x * blockDim.x + threadIdx.x;
    if (i < NN * RR) cnt[i] = 1.0f / fmaxf(cnt[i], 1.0f);
}

__global__ void rel_prefix(const int* __restrict__ rcnt, int* __restrict__ roff,
                           int* __restrict__ rcur, int* __restrict__ tbase) {
    int off = 0, tb = 0;
    for (int r = 0; r < RR; ++r) {
        roff[r] = off;
        rcur[r] = off;
        tbase[r] = tb;
        off += rcnt[r];
        tb += (rcnt[r] + TILE_E - 1) / TILE_E;
    }
    roff[RR] = off;
    tbase[RR] = tb;
}

__global__ void rel_scatter(const int* __restrict__ et, int* __restrict__ rcur,
                            int* __restrict__ bucket) {
    int e = blockIdx.x * blockDim.x + threadIdx.x;
    int lane = threadIdx.x & 63;
    int r = (e < EE) ? et[e] : -1;
    for (int rr = 0; rr < RR; ++rr) {
        unsigned long long mask = __ballot(r == rr);
        if (mask == 0ull) continue;
        int leader = __ffsll((unsigned long long)mask) - 1;
        int base = 0;
        if (lane == leader) base = atomicAdd(&rcur[rr], __popcll(mask));
        base = __shfl(base, leader);
        if (r == rr) {
            int pos = base + __popcll(mask & ((1ull << lane) - 1ull));
            bucket[pos] = e;
        }
    }
}

// out[n, j] = bias[j] + sum_i in[n, i] * root[i, j]   (full write, no accumulate)
__global__ __launch_bounds__(128) void root_bias(const float* __restrict__ in,
                                                 const float* __restrict__ root,
                                                 const float* __restrict__ bias,
                                                 float* __restrict__ out) {
    __shared__ float xr[DD];
    int n = blockIdx.x, j = threadIdx.x;
    xr[j] = in[n * DD + j];
    __syncthreads();
    float acc = bias[j];
#pragma unroll 16
    for (int i = 0; i < DD; ++i) acc = fmaf(xr[i], root[i * DD + j], acc);
    out[n * DD + j] = acc;
}

__global__ void relu_k(float* __restrict__ p, int n) {
    int i = blockIdx.x * blockDim.x + threadIdx.x;
    if (i < n) p[i] = fmaxf(p[i], 0.f);
}

// ---------------- edge GEMM: one block = 64 edges of one relation ----------------
// Y[64e][128d] = X[src_e][:] @ blockdiag(W[r,0], W[r,1]); atomic-scatter Y*inv into out.
// 256 threads, micro-tile 4 edges x 8 dims (32 acc). LDS: XT (transposed X), WS (both W halves).
__global__ __launch_bounds__(256) void edge_gemm(
    const float* __restrict__ x, const int* __restrict__ bucket,
    const int* __restrict__ src, const int* __restrict__ dst,
    const float* __restrict__ W, const float* __restrict__ inv,
    const int* __restrict__ roff, const int* __restrict__ rcnt,
    const int* __restrict__ tbase, float* __restrict__ out) {

    __shared__ float XT[128][TILE_E + 4];   // XT[k][e]; pad 68 keeps rows 16B-aligned, 2-way banks
    __shared__ float WS[2][64][64];
    __shared__ int   edst[TILE_E];
    __shared__ float escale[TILE_E];

    int bid = blockIdx.x;
    if (bid >= tbase[RR]) return;
    int r = 0;
    while (bid >= tbase[r + 1]) ++r;       // <=8 iters, wave-uniform
    int t = bid - tbase[r];
    int nE = rcnt[r];
    int base = roff[r] + t * TILE_E;
    int m = min(TILE_E, nE - t * TILE_E);

    int tid = threadIdx.x;
    int e = tid & 63, q = tid >> 6;        // lane-edge, quarter (wave-uniform)

    // stage W[r] (both 64x64 halves, 8192 floats) via float4, coalesced
    const float4* Wv = (const float4*)(W + (size_t)r * 2 * 64 * 64);
    float4* WSv = (float4*)&WS[0][0][0];
#pragma unroll
    for (int i = 0; i < 8; ++i) WSv[tid * 8 + i] = Wv[tid * 8 + i];

    // stage X transposed: lane e owns edge e, wave q owns k-range [q*32, q*32+32)
    if (e < m) {
        int eid = bucket[base + e];
        int s = src[eid];
        const float4* xr = (const float4*)(x + (size_t)s * DD + q * 32);
#pragma unroll
        for (int i = 0; i < 8; ++i) {
            float4 v = xr[i];
            int k = q * 32 + i * 4;
            XT[k + 0][e] = v.x; XT[k + 1][e] = v.y; XT[k + 2][e] = v.z; XT[k + 3][e] = v.w;
        }
        if (q == 0) {
            int d = dst[eid];
            edst[e] = d;
            escale[e] = inv[d * RR + r];
        }
    } else {
#pragma unroll
        for (int i = 0; i < 8; ++i) {
            int k = q * 32 + i * 4;
            XT[k + 0][e] = 0.f; XT[k + 1][e] = 0.f; XT[k + 2][e] = 0.f; XT[k + 3][e] = 0.f;
        }
    }
    __syncthreads();

    // micro-tile: eg = tid%16 -> edges 4eg..4eg+3 ; dg = tid/16 -> dims 8dg..8dg+7
    int eg = tid & 15, dg = tid >> 4;
    int e0 = eg * 4, d0 = dg * 8;
    int b = d0 >> 6;                        // wave-uniform half
    int dl = d0 & 63;
    int koff = b * 64;

    float acc[4][8];
#pragma unroll
    for (int i = 0; i < 4; ++i)
#pragma unroll
        for (int j = 0; j < 8; ++j) acc[i][j] = 0.f;

#pragma unroll 4
    for (int k = 0; k < 64; ++k) {
        float4 xv = *(const float4*)&XT[koff + k][e0];
        float4 w0 = *(const float4*)&WS[b][k][dl];
        float4 w1 = *(const float4*)&WS[b][k][dl + 4];
        float xs4[4] = {xv.x, xv.y, xv.z, xv.w};
        float wk[8]  = {w0.x, w0.y, w0.z, w0.w, w1.x, w1.y, w1.z, w1.w};
#pragma unroll
        for (int i = 0; i < 4; ++i)
#pragma unroll
            for (int j = 0; j < 8; ++j) acc[i][j] = fmaf(xs4[i], wk[j], acc[i][j]);
    }

    // atomic scatter epilogue
#pragma unroll
    for (int i = 0; i < 4; ++i) {
        int ee = e0 + i;
        if (ee < m) {
            float sc = escale[ee];
            float* op = out + (size_t)edst[ee] * DD + d0;
#pragma unroll
            for (int j = 0; j < 8; ++j) atomicAdd(&op[j], acc[i][j] * sc);
        }
    }
}

// ---------------- driver ----------------

extern "C" void kernel_launch(void* const* d_in, const int* in_sizes, int n_in,
                              void* d_out, int out_size, void* d_ws, size_t ws_size,
                              hipStream_t stream) {
    const float* x     = (const float*)d_in[0];
    const int*   ei    = (const int*)d_in[1];
    const int*   src   = ei;
    const int*   dstp  = ei + EE;
    const int*   et    = (const int*)d_in[2];
    const float* W1    = (const float*)d_in[3];
    const float* root1 = (const float*)d_in[4];
    const float* b1    = (const float*)d_in[5];
    const float* W2    = (const float*)d_in[6];
    const float* root2 = (const float*)d_in[7];
    const float* b2    = (const float*)d_in[8];
    float* out = (float*)d_out;

    // ws layout
    float* cnt    = (float*)d_ws;            // N*R: counts -> inverted in place
    float* h      = cnt + NN * RR;           // N*D: layer-1 activations
    int*   bucket = (int*)(h + NN * DD);     // E: edge ids grouped by relation
    int*   rcnt   = bucket + EE;             // 8
    int*   roff   = rcnt + RR;               // 9
    int*   rcur   = roff + RR + 1;           // 8
    int*   tbase  = rcur + RR;               // 9

    hipMemsetAsync(cnt, 0, NN * RR * sizeof(float), stream);
    hipMemsetAsync(rcnt, 0, RR * sizeof(int), stream);

    count_and_hist<<<EE / 256, 256, 0, stream>>>(dstp, et, cnt, rcnt);
    invert_cnt<<<(NN * RR + 255) / 256, 256, 0, stream>>>(cnt);
    rel_prefix<<<1, 1, 0, stream>>>(rcnt, roff, rcur, tbase);
    rel_scatter<<<EE / 256, 256, 0, stream>>>(et, rcur, bucket);

    // layer 1
    root_bias<<<NN, DD, 0, stream>>>(x, root1, b1, h);
    edge_gemm<<<MAX_TILES, 256, 0, stream>>>(x, bucket, src, dstp, W1, cnt,
                                             roff, rcnt, tbase, h);
    relu_k<<<(NN * DD + 255) / 256, 256, 0, stream>>>(h, NN * DD);

    // layer 2
    root_bias<<<NN, DD, 0, stream>>>(h, root2, b2, out);
    edge_gemm<<<MAX_TILES, 256, 0, stream>>>(h, bucket, src, dstp, W2, cnt,
                                             roff, rcnt, tbase, out);
}

// Round 3
// 3559.149 us; speedup vs baseline: 2.2711x; 2.2711x over previous
//
#include <hip/hip_runtime.h>

#define NN 50000
#define EE 800000
#define DD 128
#define RR 8
#define TILE_E 64
#define MAX_TILES (EE / TILE_E + RR)   // upper bound on sum_r ceil(E_r/64)

// ---------------- small prep kernels ----------------

__global__ void count_and_hist(const int* __restrict__ dst, const int* __restrict__ et,
                               float* __restrict__ cnt, int* __restrict__ rcnt) {
    int e = blockIdx.x * blockDim.x + threadIdx.x;
    int lane = threadIdx.x & 63;
    int r = (e < EE) ? et[e] : -1;
    if (e < EE) atomicAdd(&cnt[dst[e] * RR + r], 1.0f);
    for (int rr = 0; rr < RR; ++rr) {
        unsigned long long mask = __ballot(r == rr);
        if (mask == 0ull) continue;
        int leader = __ffsll((unsigned long long)mask) - 1;
        if (lane == leader) atomicAdd(&rcnt[rr], __popcll(mask));
    }
}

__global__ void invert_cnt(float* __restrict__ cnt) {
    int i = blockIdx.x * blockDim.x + threadIdx.x;
    if (i < NN * RR) cnt[i] = 1.0f / fmaxf(cnt[i], 1.0f);
}

__global__ void rel_prefix(const int* __restrict__ rcnt, int* __restrict__ roff,
                           int* __restrict__ rcur, int* __restrict__ tbase) {
    int off = 0, tb = 0;
    for (int r = 0; r < RR; ++r) {
        roff[r] = off;
        rcur[r] = off;
        tbase[r] = tb;
        off += rcnt[r];
        tb += (rcnt[r] + TILE_E - 1) / TILE_E;
    }
    roff[RR] = off;
    tbase[RR] = tb;
}

__global__ void rel_scatter(const int* __restrict__ et, int* __restrict__ rcur,
                            int* __restrict__ bucket) {
    int e = blockIdx.x * blockDim.x + threadIdx.x;
    int lane = threadIdx.x & 63;
    int r = (e < EE) ? et[e] : -1;
    for (int rr = 0; rr < RR; ++rr) {
        unsigned long long mask = __ballot(r == rr);
        if (mask == 0ull) continue;
        int leader = __ffsll((unsigned long long)mask) - 1;
        int base = 0;
        if (lane == leader) base = atomicAdd(&rcur[rr], __popcll(mask));
        base = __shfl(base, leader);
        if (r == rr) {
            int pos = base + __popcll(mask & ((1ull << lane) - 1ull));
            bucket[pos] = e;
        }
    }
}

// out[n, j] = bias[j] + sum_i in[n, i] * root[i, j]   (full write, no accumulate)
__global__ __launch_bounds__(128) void root_bias(const float* __restrict__ in,
                                                 const float* __restrict__ root,
                                                 const float* __restrict__ bias,
                                                 float* __restrict__ out) {
    __shared__ float xr[DD];
    int n = blockIdx.x, j = threadIdx.x;
    xr[j] = in[n * DD + j];
    __syncthreads();
    float acc = bias[j];
#pragma unroll 16
    for (int i = 0; i < DD; ++i) acc = fmaf(xr[i], root[i * DD + j], acc);
    out[n * DD + j] = acc;
}

__global__ void relu_k(float* __restrict__ p, int n) {
    int i = blockIdx.x * blockDim.x + threadIdx.x;
    if (i < n) p[i] = fmaxf(p[i], 0.f);
}

// ---------------- edge GEMM: one block = 64 edges of one relation ----------------
// Y[64e][128d] = X[src_e][:] @ blockdiag(W[r,0], W[r,1]); result staged in LDS,
// then atomic-scattered with thread<->dim ownership (coalesced atomics).
__global__ __launch_bounds__(256) void edge_gemm(
    const float* __restrict__ x, const int* __restrict__ bucket,
    const int* __restrict__ src, const int* __restrict__ dst,
    const float* __restrict__ W, const float* __restrict__ inv,
    const int* __restrict__ roff, const int* __restrict__ rcnt,
    const int* __restrict__ tbase, float* __restrict__ out) {

    __shared__ float XT[128][66];          // XT[k][e]; reused as Ys[64][129] in epilogue
    __shared__ float WS[2][64][64];
    __shared__ int   edst[TILE_E];
    __shared__ float escale[TILE_E];

    int bid = blockIdx.x;
    if (bid >= tbase[RR]) return;
    int r = 0;
    while (bid >= tbase[r + 1]) ++r;       // <=8 iters, wave-uniform
    int t = bid - tbase[r];
    int nE = rcnt[r];
    int base = roff[r] + t * TILE_E;
    int m = min(TILE_E, nE - t * TILE_E);

    int tid = threadIdx.x;
    int e = tid & 63, q = tid >> 6;        // lane-edge, quarter (wave-uniform)

    // stage W[r] (both 64x64 halves, 8192 floats) via float4, coalesced
    const float4* Wv = (const float4*)(W + (size_t)r * 2 * 64 * 64);
    float4* WSv = (float4*)&WS[0][0][0];
#pragma unroll
    for (int i = 0; i < 8; ++i) WSv[tid * 8 + i] = Wv[tid * 8 + i];

    // stage X transposed: lane e owns edge e, wave q owns k-range [q*32, q*32+32)
    if (e < m) {
        int eid = bucket[base + e];
        int s = src[eid];
        const float4* xr = (const float4*)(x + (size_t)s * DD + q * 32);
#pragma unroll
        for (int i = 0; i < 8; ++i) {
            float4 v = xr[i];
            int k = q * 32 + i * 4;
            XT[k + 0][e] = v.x; XT[k + 1][e] = v.y; XT[k + 2][e] = v.z; XT[k + 3][e] = v.w;
        }
        if (q == 0) {
            int d = dst[eid];
            edst[e] = d;
            escale[e] = inv[d * RR + r];
        }
    } else {
#pragma unroll
        for (int i = 0; i < 8; ++i) {
            int k = q * 32 + i * 4;
            XT[k + 0][e] = 0.f; XT[k + 1][e] = 0.f; XT[k + 2][e] = 0.f; XT[k + 3][e] = 0.f;
        }
    }
    __syncthreads();

    // micro-tile: eg = tid%16 -> edges 4eg..4eg+3 ; dg = tid/16 -> dims 8dg..8dg+7
    int eg = tid & 15, dg = tid >> 4;
    int e0 = eg * 4, d0 = dg * 8;
    int b = d0 >> 6;                        // wave-uniform half
    int dl = d0 & 63;
    int koff = b * 64;

    float acc[4][8];
#pragma unroll
    for (int i = 0; i < 4; ++i)
#pragma unroll
        for (int j = 0; j < 8; ++j) acc[i][j] = 0.f;

#pragma unroll 4
    for (int k = 0; k < 64; ++k) {
        float4 xv = *(const float4*)&XT[koff + k][e0];
        float4 w0 = *(const float4*)&WS[b][k][dl];
        float4 w1 = *(const float4*)&WS[b][k][dl + 4];
        float xs4[4] = {xv.x, xv.y, xv.z, xv.w};
        float wk[8]  = {w0.x, w0.y, w0.z, w0.w, w1.x, w1.y, w1.z, w1.w};
#pragma unroll
        for (int i = 0; i < 4; ++i)
#pragma unroll
            for (int j = 0; j < 8; ++j) acc[i][j] = fmaf(xs4[i], wk[j], acc[i][j]);
    }

    // stage result tile into LDS (reuse XT as Ys[64][129])
    __syncthreads();
    float* Ys = &XT[0][0];
#pragma unroll
    for (int i = 0; i < 4; ++i)
#pragma unroll
        for (int j = 0; j < 8; ++j)
            Ys[(e0 + i) * 129 + d0 + j] = acc[i][j];
    __syncthreads();

    // coalesced atomic scatter: 2 edges x 128 dims per iteration
    int d = tid & 127;
    int half = tid >> 7;
#pragma unroll 4
    for (int it = 0; it < TILE_E / 2; ++it) {
        int ee = it * 2 + half;
        if (ee < m) {
            float v = Ys[ee * 129 + d] * escale[ee];
            atomicAdd(&out[(size_t)edst[ee] * DD + d], v);
        }
    }
}

// ---------------- driver ----------------

extern "C" void kernel_launch(void* const* d_in, const int* in_sizes, int n_in,
                              void* d_out, int out_size, void* d_ws, size_t ws_size,
                              hipStream_t stream) {
    const float* x     = (const float*)d_in[0];
    const int*   ei    = (const int*)d_in[1];
    const int*   src   = ei;
    const int*   dstp  = ei + EE;
    const int*   et    = (const int*)d_in[2];
    const float* W1    = (const float*)d_in[3];
    const float* root1 = (const float*)d_in[4];
    const float* b1    = (const float*)d_in[5];
    const float* W2    = (const float*)d_in[6];
    const float* root2 = (const float*)d_in[7];
    const float* b2    = (const float*)d_in[8];
    float* out = (float*)d_out;

    // ws layout
    float* cnt    = (float*)d_ws;            // N*R: counts -> inverted in place
    float* h      = cnt + NN * RR;           // N*D: layer-1 activations
    int*   bucket = (int*)(h + NN * DD);     // E: edge ids grouped by relation
    int*   rcnt   = bucket + EE;             // 8
    int*   roff   = rcnt + RR;               // 9
    int*   rcur   = roff + RR + 1;           // 8
    int*   tbase  = rcur + RR;               // 9

    hipMemsetAsync(cnt, 0, NN * RR * sizeof(float), stream);
    hipMemsetAsync(rcnt, 0, RR * sizeof(int), stream);

    count_and_hist<<<EE / 256, 256, 0, stream>>>(dstp, et, cnt, rcnt);
    invert_cnt<<<(NN * RR + 255) / 256, 256, 0, stream>>>(cnt);
    rel_prefix<<<1, 1, 0, stream>>>(rcnt, roff, rcur, tbase);
    rel_scatter<<<EE / 256, 256, 0, stream>>>(et, rcur, bucket);

    // layer 1
    root_bias<<<NN, DD, 0, stream>>>(x, root1, b1, h);
    edge_gemm<<<MAX_TILES, 256, 0, stream>>>(x, bucket, src, dstp, W1, cnt,
                                             roff, rcnt, tbase, h);
    relu_k<<<(NN * DD + 255) / 256, 256, 0, stream>>>(h, NN * DD);

    // layer 2
    root_bias<<<NN, DD, 0, stream>>>(h, root2, b2, out);
    edge_gemm<<<MAX_TILES, 256, 0, stream>>>(h, bucket, src, dstp, W2, cnt,
                                             roff, rcnt, tbase, out);
}

// Round 4
// 1142.430 us; speedup vs baseline: 7.0755x; 3.1154x over previous
//
#include <hip/hip_runtime.h>

#define NN 50000
#define EE 800000
#define DD 128
#define RR 8
#define TILE_E 64
#define MAX_TILES (EE / TILE_E + RR)   // upper bound on sum_r ceil(E_r/64)
#define PREP_BLOCKS 256

// ---------------- small prep kernels ----------------

// per-(dst,rel) fp32 counts (scattered atomics: fast) + per-relation histogram
// via LDS bins, one global atomic per (block, relation) -> 2048 total.
__global__ void count_hist(const int* __restrict__ dst, const int* __restrict__ et,
                           float* __restrict__ cnt, int* __restrict__ rcnt) {
    __shared__ int lh[RR];
    int tid = threadIdx.x;
    if (tid < RR) lh[tid] = 0;
    __syncthreads();
    int stride = gridDim.x * blockDim.x;
    for (int e = blockIdx.x * blockDim.x + tid; e < EE; e += stride) {
        int r = et[e];
        atomicAdd(&cnt[dst[e] * RR + r], 1.0f);
        atomicAdd(&lh[r], 1);
    }
    __syncthreads();
    if (tid < RR) atomicAdd(&rcnt[tid], lh[tid]);
}

__global__ void invert_cnt(float* __restrict__ cnt) {
    int i = blockIdx.x * blockDim.x + threadIdx.x;
    if (i < NN * RR) cnt[i] = 1.0f / fmaxf(cnt[i], 1.0f);
}

__global__ void rel_prefix(const int* __restrict__ rcnt, int* __restrict__ roff,
                           int* __restrict__ rcur, int* __restrict__ tbase) {
    int off = 0, tb = 0;
    for (int r = 0; r < RR; ++r) {
        roff[r] = off;
        rcur[r] = off;
        tbase[r] = tb;
        off += rcnt[r];
        tb += (rcnt[r] + TILE_E - 1) / TILE_E;
    }
    roff[RR] = off;
    tbase[RR] = tb;
}

// bucket edges by relation: block-local LDS counting, one range-reservation
// atomic per (block, relation), then LDS-allocated placement.
__global__ void rel_scatter(const int* __restrict__ et, int* __restrict__ rcur,
                            int* __restrict__ bucket) {
    __shared__ int lh[RR];
    __shared__ int lbase[RR];
    int tid = threadIdx.x;
    if (tid < RR) lh[tid] = 0;
    __syncthreads();
    int stride = gridDim.x * blockDim.x;
    for (int e = blockIdx.x * blockDim.x + tid; e < EE; e += stride)
        atomicAdd(&lh[et[e]], 1);
    __syncthreads();
    if (tid < RR) {
        lbase[tid] = atomicAdd(&rcur[tid], lh[tid]);
        lh[tid] = 0;
    }
    __syncthreads();
    for (int e = blockIdx.x * blockDim.x + tid; e < EE; e += stride) {
        int r = et[e];
        int p = atomicAdd(&lh[r], 1);
        bucket[lbase[r] + p] = e;
    }
}

// out[n0+u, j] = bias[j] + sum_i in[n0+u, i] * root[i, j], 8 nodes per block
// so each root element fetched from L2 once per 8 nodes.
__global__ __launch_bounds__(128) void root_bias(const float* __restrict__ in,
                                                 const float* __restrict__ root,
                                                 const float* __restrict__ bias,
                                                 float* __restrict__ out) {
    __shared__ float xr[8][DD];
    int n0 = blockIdx.x * 8, j = threadIdx.x;
#pragma unroll
    for (int u = 0; u < 8; ++u) xr[u][j] = in[(size_t)(n0 + u) * DD + j];
    __syncthreads();
    float bj = bias[j];
    float acc[8];
#pragma unroll
    for (int u = 0; u < 8; ++u) acc[u] = bj;
#pragma unroll 8
    for (int i = 0; i < DD; ++i) {
        float w = root[i * DD + j];
#pragma unroll
        for (int u = 0; u < 8; ++u) acc[u] = fmaf(xr[u][i], w, acc[u]);
    }
#pragma unroll
    for (int u = 0; u < 8; ++u) out[(size_t)(n0 + u) * DD + j] = acc[u];
}

__global__ void relu_k(float* __restrict__ p, int n) {
    int i = blockIdx.x * blockDim.x + threadIdx.x;
    if (i < n) p[i] = fmaxf(p[i], 0.f);
}

// ---------------- edge GEMM: one block = 64 edges of one relation ----------------
// Y[64e][128d] = X[src_e][:] @ blockdiag(W[r,0], W[r,1]); result staged in LDS,
// then atomic-scattered with thread<->dim ownership (coalesced atomics).
__global__ __launch_bounds__(256) void edge_gemm(
    const float* __restrict__ x, const int* __restrict__ bucket,
    const int* __restrict__ src, const int* __restrict__ dst,
    const float* __restrict__ W, const float* __restrict__ inv,
    const int* __restrict__ roff, const int* __restrict__ rcnt,
    const int* __restrict__ tbase, float* __restrict__ out) {

    __shared__ float XT[128][66];          // XT[k][e]; reused as Ys[64][129] in epilogue
    __shared__ float WS[2][64][64];
    __shared__ int   edst[TILE_E];
    __shared__ float escale[TILE_E];

    int bid = blockIdx.x;
    if (bid >= tbase[RR]) return;
    int r = 0;
    while (bid >= tbase[r + 1]) ++r;       // <=8 iters, wave-uniform
    int t = bid - tbase[r];
    int nE = rcnt[r];
    int base = roff[r] + t * TILE_E;
    int m = min(TILE_E, nE - t * TILE_E);

    int tid = threadIdx.x;
    int e = tid & 63, q = tid >> 6;        // lane-edge, quarter (wave-uniform)

    // stage W[r] (both 64x64 halves, 8192 floats) via float4, coalesced
    const float4* Wv = (const float4*)(W + (size_t)r * 2 * 64 * 64);
    float4* WSv = (float4*)&WS[0][0][0];
#pragma unroll
    for (int i = 0; i < 8; ++i) WSv[tid * 8 + i] = Wv[tid * 8 + i];

    // stage X transposed: lane e owns edge e, wave q owns k-range [q*32, q*32+32)
    if (e < m) {
        int eid = bucket[base + e];
        int s = src[eid];
        const float4* xr = (const float4*)(x + (size_t)s * DD + q * 32);
#pragma unroll
        for (int i = 0; i < 8; ++i) {
            float4 v = xr[i];
            int k = q * 32 + i * 4;
            XT[k + 0][e] = v.x; XT[k + 1][e] = v.y; XT[k + 2][e] = v.z; XT[k + 3][e] = v.w;
        }
        if (q == 0) {
            int d = dst[eid];
            edst[e] = d;
            escale[e] = inv[d * RR + r];
        }
    } else {
#pragma unroll
        for (int i = 0; i < 8; ++i) {
            int k = q * 32 + i * 4;
            XT[k + 0][e] = 0.f; XT[k + 1][e] = 0.f; XT[k + 2][e] = 0.f; XT[k + 3][e] = 0.f;
        }
    }
    __syncthreads();

    // micro-tile: eg = tid%16 -> edges 4eg..4eg+3 ; dg = tid/16 -> dims 8dg..8dg+7
    int eg = tid & 15, dg = tid >> 4;
    int e0 = eg * 4, d0 = dg * 8;
    int b = d0 >> 6;                        // wave-uniform half
    int dl = d0 & 63;
    int koff = b * 64;

    float acc[4][8];
#pragma unroll
    for (int i = 0; i < 4; ++i)
#pragma unroll
        for (int j = 0; j < 8; ++j) acc[i][j] = 0.f;

#pragma unroll 4
    for (int k = 0; k < 64; ++k) {
        float4 xv = *(const float4*)&XT[koff + k][e0];
        float4 w0 = *(const float4*)&WS[b][k][dl];
        float4 w1 = *(const float4*)&WS[b][k][dl + 4];
        float xs4[4] = {xv.x, xv.y, xv.z, xv.w};
        float wk[8]  = {w0.x, w0.y, w0.z, w0.w, w1.x, w1.y, w1.z, w1.w};
#pragma unroll
        for (int i = 0; i < 4; ++i)
#pragma unroll
            for (int j = 0; j < 8; ++j) acc[i][j] = fmaf(xs4[i], wk[j], acc[i][j]);
    }

    // stage result tile into LDS (reuse XT as Ys[64][129])
    __syncthreads();
    float* Ys = &XT[0][0];
#pragma unroll
    for (int i = 0; i < 4; ++i)
#pragma unroll
        for (int j = 0; j < 8; ++j)
            Ys[(e0 + i) * 129 + d0 + j] = acc[i][j];
    __syncthreads();

    // coalesced atomic scatter: 2 edges x 128 dims per iteration
    int d = tid & 127;
    int half = tid >> 7;
#pragma unroll 4
    for (int it = 0; it < TILE_E / 2; ++it) {
        int ee = it * 2 + half;
        if (ee < m) {
            float v = Ys[ee * 129 + d] * escale[ee];
            atomicAdd(&out[(size_t)edst[ee] * DD + d], v);
        }
    }
}

// ---------------- driver ----------------

extern "C" void kernel_launch(void* const* d_in, const int* in_sizes, int n_in,
                              void* d_out, int out_size, void* d_ws, size_t ws_size,
                              hipStream_t stream) {
    const float* x     = (const float*)d_in[0];
    const int*   ei    = (const int*)d_in[1];
    const int*   src   = ei;
    const int*   dstp  = ei + EE;
    const int*   et    = (const int*)d_in[2];
    const float* W1    = (const float*)d_in[3];
    const float* root1 = (const float*)d_in[4];
    const float* b1    = (const float*)d_in[5];
    const float* W2    = (const float*)d_in[6];
    const float* root2 = (const float*)d_in[7];
    const float* b2    = (const float*)d_in[8];
    float* out = (float*)d_out;

    // ws layout
    float* cnt    = (float*)d_ws;            // N*R: counts -> inverted in place
    float* h      = cnt + NN * RR;           // N*D: layer-1 activations
    int*   bucket = (int*)(h + NN * DD);     // E: edge ids grouped by relation
    int*   rcnt   = bucket + EE;             // 8
    int*   roff   = rcnt + RR;               // 9
    int*   rcur   = roff + RR + 1;           // 8
    int*   tbase  = rcur + RR;               // 9

    hipMemsetAsync(cnt, 0, NN * RR * sizeof(float), stream);
    hipMemsetAsync(rcnt, 0, RR * sizeof(int), stream);

    count_hist<<<PREP_BLOCKS, 256, 0, stream>>>(dstp, et, cnt, rcnt);
    invert_cnt<<<(NN * RR + 255) / 256, 256, 0, stream>>>(cnt);
    rel_prefix<<<1, 1, 0, stream>>>(rcnt, roff, rcur, tbase);
    rel_scatter<<<PREP_BLOCKS, 256, 0, stream>>>(et, rcur, bucket);

    // layer 1
    root_bias<<<NN / 8, DD, 0, stream>>>(x, root1, b1, h);
    edge_gemm<<<MAX_TILES, 256, 0, stream>>>(x, bucket, src, dstp, W1, cnt,
                                             roff, rcnt, tbase, h);
    relu_k<<<(NN * DD + 255) / 256, 256, 0, stream>>>(h, NN * DD);

    // layer 2
    root_bias<<<NN / 8, DD, 0, stream>>>(h, root2, b2, out);
    edge_gemm<<<MAX_TILES, 256, 0, stream>>>(h, bucket, src, dstp, W2, cnt,
                                             roff, rcnt, tbase, out);
}

// Round 5
// 627.164 us; speedup vs baseline: 12.8887x; 1.8216x over previous
//
#include <hip/hip_runtime.h>

#define NN 50000
#define EE 800000
#define DD 128
#define RR 8
#define CELLS (NN * RR)            // 400000 (dst, rel) cells
#define TILE_N 64
#define NBLK ((NN + TILE_N - 1) / TILE_N)          // 782
#define SCAN_CHUNK 1024
#define SCAN_BLOCKS ((CELLS + SCAN_CHUNK - 1) / SCAN_CHUNK)   // 391

// ---------------- prep: counting sort into CSR by cell = dst*8 + rel ----------------

__global__ void count_cells(const int* __restrict__ dst, const int* __restrict__ et,
                            int* __restrict__ cnt) {
    int stride = gridDim.x * blockDim.x;
    for (int e = blockIdx.x * blockDim.x + threadIdx.x; e < EE; e += stride)
        atomicAdd(&cnt[dst[e] * RR + et[e]], 1);
}

// block-local exclusive scan over 1024 cells (4/thread), block total to bsum
__global__ __launch_bounds__(256) void scan1(const int* __restrict__ cnt,
                                             int* __restrict__ off, int* __restrict__ bsum) {
    __shared__ int s[256];
    int tid = threadIdx.x;
    int base = blockIdx.x * SCAN_CHUNK + tid * 4;
    int v[4];
#pragma unroll
    for (int i = 0; i < 4; ++i) v[i] = (base + i < CELLS) ? cnt[base + i] : 0;
    int tot = v[0] + v[1] + v[2] + v[3];
    s[tid] = tot;
    __syncthreads();
    for (int d = 1; d < 256; d <<= 1) {
        int t = (tid >= d) ? s[tid - d] : 0;
        __syncthreads();
        s[tid] += t;
        __syncthreads();
    }
    int excl = s[tid] - tot;
    if (tid == 255) bsum[blockIdx.x] = s[255];
    int run = excl;
#pragma unroll
    for (int i = 0; i < 4; ++i) {
        if (base + i < CELLS) off[base + i] = run;
        run += v[i];
    }
}

// exclusive scan of the block sums (SCAN_BLOCKS <= 512), in place
__global__ __launch_bounds__(512) void scan2(int* __restrict__ bsum) {
    __shared__ int s[512];
    int tid = threadIdx.x;
    int v = (tid < SCAN_BLOCKS) ? bsum[tid] : 0;
    s[tid] = v;
    __syncthreads();
    for (int d = 1; d < 512; d <<= 1) {
        int t = (tid >= d) ? s[tid - d] : 0;
        __syncthreads();
        s[tid] += t;
        __syncthreads();
    }
    if (tid < SCAN_BLOCKS) bsum[tid] = s[tid] - v;
}

// add block bases; make the mutable cursor copy
__global__ __launch_bounds__(256) void scan3(int* __restrict__ off, const int* __restrict__ bsum,
                                             int* __restrict__ cur) {
    int base = blockIdx.x * SCAN_CHUNK + threadIdx.x * 4;
    int add = bsum[blockIdx.x];
#pragma unroll
    for (int i = 0; i < 4; ++i) {
        int c = base + i;
        if (c < CELLS) {
            int o = off[c] + add;
            off[c] = o;
            cur[c] = o;
        }
    }
}

__global__ void cell_scatter(const int* __restrict__ src, const int* __restrict__ dst,
                             const int* __restrict__ et, int* __restrict__ cur,
                             int* __restrict__ esrc) {
    int stride = gridDim.x * blockDim.x;
    for (int e = blockIdx.x * blockDim.x + threadIdx.x; e < EE; e += stride) {
        int cell = dst[e] * RR + et[e];
        int pos = atomicAdd(&cur[cell], 1);
        esrc[pos] = src[e];
    }
}

// ---------------- fused layer: per 64-node tile, all 8 relations + root + bias ----------------
// out[n] = (relu?)( bias + sum_r mean_{e in (n,r)} x[src_e] @ blockdiag(W[r]) + x[n] @ root )
template <int RELU>
__global__ __launch_bounds__(256) void layer_fused(
    const float* __restrict__ xin, const int* __restrict__ esrc,
    const int* __restrict__ off, const int* __restrict__ cnt,
    const float* __restrict__ W, const float* __restrict__ root,
    const float* __restrict__ bias, float* __restrict__ out) {

    __shared__ float MT[128][TILE_N];   // MT[k][n] — unpadded: col writes & float4 row reads are conflict-free
    __shared__ float WS[8192];          // rel iters: [b][k][dl] (2*64*64); root iters: [k][d] (64*128)

    int tid = threadIdx.x;
    int n0 = blockIdx.x * TILE_N;
    int e = tid & 63, q = tid >> 6;     // gather: lane-node, wave k-quarter
    int eg = tid & 15, dg = tid >> 4;   // gemm micro-tile: 4 nodes x 8 dims
    int e0 = eg * 4, d0 = dg * 8;
    int b = d0 >> 6, dl = d0 & 63;

    float acc[4][8];
    {
        float4 bv0 = *(const float4*)(bias + d0);
        float4 bv1 = *(const float4*)(bias + d0 + 4);
#pragma unroll
        for (int i = 0; i < 4; ++i) {
            acc[i][0] = bv0.x; acc[i][1] = bv0.y; acc[i][2] = bv0.z; acc[i][3] = bv0.w;
            acc[i][4] = bv1.x; acc[i][5] = bv1.y; acc[i][6] = bv1.z; acc[i][7] = bv1.w;
        }
    }

    int node = n0 + e;

    for (int r = 0; r < RR; ++r) {
        // stage W[r] (8192 floats)
        const float4* Wv = (const float4*)(W + (size_t)r * 8192);
        float4* WSv = (float4*)WS;
#pragma unroll
        for (int i = 0; i < 8; ++i) WSv[tid * 8 + i] = Wv[tid * 8 + i];

        // gather mean of x[src] over this node's (node, r) segment; wave q owns k in [32q, 32q+32)
        float4 s[8];
#pragma unroll
        for (int i = 0; i < 8; ++i) s[i] = make_float4(0.f, 0.f, 0.f, 0.f);
        int ne = 0;
        if (node < NN) {
            int cell = node * RR + r;
            int o = off[cell];
            ne = cnt[cell];
            for (int t2 = 0; t2 < ne; ++t2) {
                const float4* xr = (const float4*)(xin + (size_t)esrc[o + t2] * DD + q * 32);
#pragma unroll
                for (int i = 0; i < 8; ++i) {
                    float4 v = xr[i];
                    s[i].x += v.x; s[i].y += v.y; s[i].z += v.z; s[i].w += v.w;
                }
            }
        }
        float sc = 1.0f / (float)max(ne, 1);
#pragma unroll
        for (int i = 0; i < 8; ++i) {
            int k = q * 32 + i * 4;
            MT[k + 0][e] = s[i].x * sc; MT[k + 1][e] = s[i].y * sc;
            MT[k + 2][e] = s[i].z * sc; MT[k + 3][e] = s[i].w * sc;
        }
        __syncthreads();

        // block-diag GEMM accumulate: out-half b uses k-half b
#pragma unroll 4
        for (int k = 0; k < 64; ++k) {
            float4 xv = *(const float4*)&MT[b * 64 + k][e0];
            float4 w0 = *(const float4*)&WS[b * 4096 + k * 64 + dl];
            float4 w1 = *(const float4*)&WS[b * 4096 + k * 64 + dl + 4];
            float xs4[4] = {xv.x, xv.y, xv.z, xv.w};
            float wk[8]  = {w0.x, w0.y, w0.z, w0.w, w1.x, w1.y, w1.z, w1.w};
#pragma unroll
            for (int i = 0; i < 4; ++i)
#pragma unroll
                for (int j = 0; j < 8; ++j) acc[i][j] = fmaf(xs4[i], wk[j], acc[i][j]);
        }
        __syncthreads();
    }

    // root term: MT = xin rows of this tile (all 128 k), then 2 K-split dense GEMMs
    if (node < NN) {
        const float4* xr = (const float4*)(xin + (size_t)node * DD + q * 32);
#pragma unroll
        for (int i = 0; i < 8; ++i) {
            float4 v = xr[i];
            int k = q * 32 + i * 4;
            MT[k + 0][e] = v.x; MT[k + 1][e] = v.y; MT[k + 2][e] = v.z; MT[k + 3][e] = v.w;
        }
    } else {
#pragma unroll
        for (int i = 0; i < 8; ++i) {
            int k = q * 32 + i * 4;
            MT[k + 0][e] = 0.f; MT[k + 1][e] = 0.f; MT[k + 2][e] = 0.f; MT[k + 3][e] = 0.f;
        }
    }
    for (int c = 0; c < 2; ++c) {
        const float4* Rv = (const float4*)(root + c * 8192);
        float4* WSv = (float4*)WS;
#pragma unroll
        for (int i = 0; i < 8; ++i) WSv[tid * 8 + i] = Rv[tid * 8 + i];
        __syncthreads();
#pragma unroll 4
        for (int k = 0; k < 64; ++k) {
            float4 xv = *(const float4*)&MT[c * 64 + k][e0];
            float4 w0 = *(const float4*)&WS[k * 128 + d0];
            float4 w1 = *(const float4*)&WS[k * 128 + d0 + 4];
            float xs4[4] = {xv.x, xv.y, xv.z, xv.w};
            float wk[8]  = {w0.x, w0.y, w0.z, w0.w, w1.x, w1.y, w1.z, w1.w};
#pragma unroll
            for (int i = 0; i < 4; ++i)
#pragma unroll
                for (int j = 0; j < 8; ++j) acc[i][j] = fmaf(xs4[i], wk[j], acc[i][j]);
        }
        __syncthreads();
    }

    // epilogue: plain coalesced stores
#pragma unroll
    for (int i = 0; i < 4; ++i) {
        int row = n0 + e0 + i;
        if (row < NN) {
            float4 o0, o1;
            if (RELU) {
                o0 = make_float4(fmaxf(acc[i][0], 0.f), fmaxf(acc[i][1], 0.f),
                                 fmaxf(acc[i][2], 0.f), fmaxf(acc[i][3], 0.f));
                o1 = make_float4(fmaxf(acc[i][4], 0.f), fmaxf(acc[i][5], 0.f),
                                 fmaxf(acc[i][6], 0.f), fmaxf(acc[i][7], 0.f));
            } else {
                o0 = make_float4(acc[i][0], acc[i][1], acc[i][2], acc[i][3]);
                o1 = make_float4(acc[i][4], acc[i][5], acc[i][6], acc[i][7]);
            }
            *(float4*)(out + (size_t)row * DD + d0)     = o0;
            *(float4*)(out + (size_t)row * DD + d0 + 4) = o1;
        }
    }
}

// ---------------- driver ----------------

extern "C" void kernel_launch(void* const* d_in, const int* in_sizes, int n_in,
                              void* d_out, int out_size, void* d_ws, size_t ws_size,
                              hipStream_t stream) {
    const float* x     = (const float*)d_in[0];
    const int*   ei    = (const int*)d_in[1];
    const int*   src   = ei;
    const int*   dstp  = ei + EE;
    const int*   et    = (const int*)d_in[2];
    const float* W1    = (const float*)d_in[3];
    const float* root1 = (const float*)d_in[4];
    const float* b1    = (const float*)d_in[5];
    const float* W2    = (const float*)d_in[6];
    const float* root2 = (const float*)d_in[7];
    const float* b2    = (const float*)d_in[8];
    float* out = (float*)d_out;

    // ws layout
    float* h     = (float*)d_ws;             // N*D: layer-1 activations
    int*   cnt   = (int*)(h + (size_t)NN * DD); // CELLS
    int*   off   = cnt + CELLS;              // CELLS
    int*   cur   = off + CELLS;              // CELLS
    int*   bsum  = cur + CELLS;              // 512
    int*   esrc  = bsum + 512;               // EE

    hipMemsetAsync(cnt, 0, CELLS * sizeof(int), stream);
    count_cells<<<256, 256, 0, stream>>>(dstp, et, cnt);
    scan1<<<SCAN_BLOCKS, 256, 0, stream>>>(cnt, off, bsum);
    scan2<<<1, 512, 0, stream>>>(bsum);
    scan3<<<SCAN_BLOCKS, 256, 0, stream>>>(off, bsum, cur);
    cell_scatter<<<256, 256, 0, stream>>>(src, dstp, et, cur, esrc);

    layer_fused<1><<<NBLK, 256, 0, stream>>>(x, esrc, off, cnt, W1, root1, b1, h);
    layer_fused<0><<<NBLK, 256, 0, stream>>>(h, esrc, off, cnt, W2, root2, b2, out);
}